// Round 1
// baseline (1456.796 us; speedup 1.0000x reference)
//
#include <hip/hip_runtime.h>
#include <math.h>

#define BATCH 512
#define TSTEPS 512
#define FDIM 64
#define HDIM 128
#define G3 384

__device__ __forceinline__ float sigf(float x) {
    return 1.0f / (1.0f + __expf(-x));
}

__device__ __forceinline__ void fma4(float& acc, float4 w, float4 v) {
    acc = fmaf(w.x, v.x, acc);
    acc = fmaf(w.y, v.y, acc);
    acc = fmaf(w.z, v.z, acc);
    acc = fmaf(w.w, v.w, acc);
}

__global__ __launch_bounds__(384, 2)
void gru_fused_fp32(const float* __restrict__ x,
                    const float* __restrict__ W_ih,
                    const float* __restrict__ W_hh,
                    const float* __restrict__ b_ih,
                    const float* __restrict__ b_hh,
                    const float* __restrict__ W_out,
                    const float* __restrict__ b_out,
                    float* __restrict__ out)
{
    const int tid = threadIdx.x;
    const int g = tid;                 // gate row 0..383
    const int b0 = blockIdx.x * 2;
    const int b1 = b0 + 1;

    __shared__ __align__(16) float h_s[2][HDIM];
    __shared__ __align__(16) float x_s[2][FDIM];
    __shared__ float r_s[2][HDIM];
    __shared__ float z_s[2][HDIM];
    __shared__ float red_s[2][2];

    // ---- load this thread's weight rows into registers ----
    float4 wih4[16];   // W_ih[g][0:64]
    float4 whh4[32];   // W_hh[g][0:128]
    {
        const float4* wi = (const float4*)(W_ih + g * FDIM);
        #pragma unroll
        for (int j = 0; j < 16; ++j) wih4[j] = wi[j];
        const float4* wh = (const float4*)(W_hh + g * HDIM);
        #pragma unroll
        for (int j = 0; j < 32; ++j) whh4[j] = wh[j];
    }
    const float bi = b_ih[g];
    const float bh = b_hh[g];
    const float wout = (g >= 256) ? W_out[g - 256] : 0.0f;
    const float bout = b_out[0];

    // ---- init h = 0, preload x for t=0 ----
    if (tid < 256) h_s[tid >> 7][tid & 127] = 0.0f;
    const float4* xg4 = (const float4*)x;
    if (tid < 32) {
        const int bb = tid >> 4;
        const int j  = tid & 15;
        ((float4*)x_s)[tid] = xg4[((bb ? b1 : b0) * TSTEPS + 0) * 16 + j];
    }

    for (int t = 0; t < TSTEPS; ++t) {
        __syncthreads();   // barrier A: h_s, x_s, red_s(prev step) all ready

        // write previous step's output (red_s was produced last phase 2)
        if (t > 0 && tid < 2)
            out[(tid ? b1 : b0) * TSTEPS + (t - 1)] =
                tanhf(red_s[tid][0] + red_s[tid][1] + bout);

        // kick off prefetch of x for t+1 (commits to LDS after barrier B)
        float4 xpre;
        const bool pf = (tid < 32) && (t + 1 < TSTEPS);
        if (pf)
            xpre = xg4[((tid >= 16 ? b1 : b0) * TSTEPS + (t + 1)) * 16 + (tid & 15)];

        // ---- dot products: gi = W_ih[g]·x + b_ih, gh = W_hh[g]·h + b_hh ----
        float di0a = bi,  di0b = 0.f, di1a = bi,  di1b = 0.f;
        float dh0a = bh,  dh0b = 0.f, dh1a = bh,  dh1b = 0.f;
        const float4* x40 = (const float4*)x_s[0];
        const float4* x41 = (const float4*)x_s[1];
        #pragma unroll
        for (int j = 0; j < 16; j += 2) {
            fma4(di0a, wih4[j],     x40[j]);
            fma4(di1a, wih4[j],     x41[j]);
            fma4(di0b, wih4[j + 1], x40[j + 1]);
            fma4(di1b, wih4[j + 1], x41[j + 1]);
        }
        const float4* h40 = (const float4*)h_s[0];
        const float4* h41 = (const float4*)h_s[1];
        #pragma unroll
        for (int j = 0; j < 32; j += 2) {
            fma4(dh0a, whh4[j],     h40[j]);
            fma4(dh1a, whh4[j],     h41[j]);
            fma4(dh0b, whh4[j + 1], h40[j + 1]);
            fma4(dh1b, whh4[j + 1], h41[j + 1]);
        }
        const float di0 = di0a + di0b, di1 = di1a + di1b;
        const float dh0 = dh0a + dh0b, dh1 = dh1a + dh1b;

        // ---- r / z gates ----
        if (g < 128) {
            r_s[0][g] = sigf(di0 + dh0);
            r_s[1][g] = sigf(di1 + dh1);
        } else if (g < 256) {
            const int k = g - 128;
            z_s[0][k] = sigf(di0 + dh0);
            z_s[1][k] = sigf(di1 + dh1);
        }
        __syncthreads();   // barrier B: r_s/z_s ready; x_s dots finished

        if (g >= 256) {
            const int k = g - 256;
            const float dinn[2] = { di0, di1 };
            const float dhnn[2] = { dh0, dh1 };
            #pragma unroll
            for (int bb = 0; bb < 2; ++bb) {
                const float n  = tanhf(dinn[bb] + r_s[bb][k] * dhnn[bb]);
                const float z  = z_s[bb][k];
                const float hn = fmaf(z, h_s[bb][k] - n, n);   // (1-z)n + z h
                h_s[bb][k] = hn;
                // output reduction: sum_k W_out[k] * h_new[k]
                float v = wout * hn;
                #pragma unroll
                for (int off = 32; off; off >>= 1) v += __shfl_xor(v, off);
                if ((tid & 63) == 0) red_s[bb][(tid >> 6) - 4] = v;
            }
        } else if (pf) {
            ((float4*)x_s)[tid] = xpre;   // commit prefetched x(t+1)
        }
    }

    __syncthreads();
    if (tid < 2)
        out[(tid ? b1 : b0) * TSTEPS + (TSTEPS - 1)] =
            tanhf(red_s[tid][0] + red_s[tid][1] + bout);
}

extern "C" void kernel_launch(void* const* d_in, const int* in_sizes, int n_in,
                              void* d_out, int out_size, void* d_ws, size_t ws_size,
                              hipStream_t stream) {
    const float* x     = (const float*)d_in[0];
    const float* W_ih  = (const float*)d_in[1];
    const float* W_hh  = (const float*)d_in[2];
    const float* b_ih  = (const float*)d_in[3];
    const float* b_hh  = (const float*)d_in[4];
    const float* W_out = (const float*)d_in[5];
    const float* b_out = (const float*)d_in[6];
    float* out = (float*)d_out;

    gru_fused_fp32<<<BATCH / 2, 384, 0, stream>>>(
        x, W_ih, W_hh, b_ih, b_hh, W_out, b_out, out);
}

// Round 2
// 1023.117 us; speedup vs baseline: 1.4239x; 1.4239x over previous
//
#include <hip/hip_runtime.h>
#include <math.h>

#define TSEQ 512
#define FDIM 64
#define HDIM 128

typedef __attribute__((ext_vector_type(8))) short short8;
typedef __attribute__((ext_vector_type(4))) float f32x4;

__device__ __forceinline__ float fast_sig(float x) {
    return __builtin_amdgcn_rcpf(1.0f + __expf(-x));
}
__device__ __forceinline__ float fast_tanh(float x) {
    return 1.0f - 2.0f * __builtin_amdgcn_rcpf(1.0f + __expf(2.0f * x));
}
__device__ __forceinline__ unsigned short bf16_rn(float v) {
    unsigned int u = __float_as_uint(v);
    u += 0x7FFF + ((u >> 16) & 1);
    return (unsigned short)(u >> 16);
}
__device__ __forceinline__ void cvt_hilo(float v, unsigned short& hi, unsigned short& lo) {
    hi = bf16_rn(v);
    float vh = __uint_as_float(((unsigned int)hi) << 16);
    lo = bf16_rn(v - vh);
}
__device__ __forceinline__ f32x4 mfma16(short8 a, short8 b, f32x4 c) {
    return __builtin_amdgcn_mfma_f32_16x16x32_bf16(a, b, c, 0, 0, 0);
}

// 32 blocks x 16 batches. 4 waves; wave w owns gate-tiles {2w,2w+1} of each of
// r/z/n  ->  r,z,n,h_old for a given (batch,h) land in the same lane.
// A-operand = weights (stationary VGPRs, hi/lo bf16 split, 3-term product),
// B-operand = h/x fragments from double-buffered LDS (1 ds_read_b128 each,
// shared across the wave's 6 gate tiles). One barrier per step.
__global__ __launch_bounds__(256, 1)
void gru_mfma(const float* __restrict__ x,
              const float* __restrict__ W_ih,
              const float* __restrict__ W_hh,
              const float* __restrict__ b_ih,
              const float* __restrict__ b_hh,
              const float* __restrict__ W_out,
              const float* __restrict__ b_out,
              float* __restrict__ out)
{
    const int tid  = threadIdx.x;
    const int w    = tid >> 6;        // wave 0..3
    const int lane = tid & 63;
    const int g4   = lane >> 4;       // k-group 0..3
    const int bcol = lane & 15;       // A: gate row within tile; B/C: batch col
    const int b0   = blockIdx.x * 16;

    __shared__ __align__(16) short h_hi_s[2][16][136];   // [buf][batch][h] +8 pad
    __shared__ __align__(16) short h_lo_s[2][16][136];
    __shared__ __align__(16) short x_hi_s[2][16][72];    // [buf][batch][f] +8 pad
    __shared__ __align__(16) short x_lo_s[2][16][72];
    __shared__ float psum_s[2][4][16];

    // ---- stationary weight A-fragments (hi/lo bf16) ----
    short8 Whh_hi[3][2][4], Whh_lo[3][2][4];   // [kind r/z/n][j][kt]
    short8 Wih_hi[3][2][2], Wih_lo[3][2][2];
    #pragma unroll
    for (int kd = 0; kd < 3; ++kd) {
        #pragma unroll
        for (int j = 0; j < 2; ++j) {
            const int g = kd * 128 + w * 32 + j * 16 + bcol;
            #pragma unroll
            for (int kt = 0; kt < 4; ++kt) {
                const float* p = W_hh + g * HDIM + kt * 32 + g4 * 8;
                short8 hi8, lo8;
                #pragma unroll
                for (int e = 0; e < 8; ++e) {
                    unsigned short h_, l_;
                    cvt_hilo(p[e], h_, l_);
                    hi8[e] = (short)h_; lo8[e] = (short)l_;
                }
                Whh_hi[kd][j][kt] = hi8; Whh_lo[kd][j][kt] = lo8;
            }
            #pragma unroll
            for (int kt = 0; kt < 2; ++kt) {
                const float* p = W_ih + g * FDIM + kt * 32 + g4 * 8;
                short8 hi8, lo8;
                #pragma unroll
                for (int e = 0; e < 8; ++e) {
                    unsigned short h_, l_;
                    cvt_hilo(p[e], h_, l_);
                    hi8[e] = (short)h_; lo8[e] = (short)l_;
                }
                Wih_hi[kd][j][kt] = hi8; Wih_lo[kd][j][kt] = lo8;
            }
        }
    }

    // ---- per-lane biases, W_out slice, persistent h_old ----
    f32x4 biasR[2], biasZ[2], biasNI[2], biasNH[2];
    float wout[2][4], h_old[2][4];
    #pragma unroll
    for (int j = 0; j < 2; ++j) {
        #pragma unroll
        for (int i = 0; i < 4; ++i) {
            const int gr = w * 32 + j * 16 + g4 * 4 + i;   // h-index 0..127
            biasR[j][i]  = b_ih[gr]       + b_hh[gr];
            biasZ[j][i]  = b_ih[128 + gr] + b_hh[128 + gr];
            biasNI[j][i] = b_ih[256 + gr];
            biasNH[j][i] = b_hh[256 + gr];
            wout[j][i]   = W_out[gr];
            h_old[j][i]  = 0.0f;
        }
    }
    const float bout = b_out[0];

    // ---- init: h buffer 0 = 0, stage x(t=0) ----
    {
        unsigned int* hp = (unsigned int*)&h_hi_s[0][0][0];
        unsigned int* lp = (unsigned int*)&h_lo_s[0][0][0];
        for (int i = tid; i < 16 * 136 / 2; i += 256) { hp[i] = 0u; lp[i] = 0u; }
    }
    const int bx = tid >> 4;
    const int fx = (tid & 15) * 4;
    {
        float4 xv = *(const float4*)(x + (size_t)(b0 + bx) * TSEQ * FDIM + fx);
        unsigned short h0,l0,h1,l1,h2,l2,h3,l3;
        cvt_hilo(xv.x,h0,l0); cvt_hilo(xv.y,h1,l1);
        cvt_hilo(xv.z,h2,l2); cvt_hilo(xv.w,h3,l3);
        uint2 ph = { (unsigned)h0 | ((unsigned)h1 << 16), (unsigned)h2 | ((unsigned)h3 << 16) };
        uint2 pl = { (unsigned)l0 | ((unsigned)l1 << 16), (unsigned)l2 | ((unsigned)l3 << 16) };
        *(uint2*)&x_hi_s[0][bx][fx] = ph;
        *(uint2*)&x_lo_s[0][bx][fx] = pl;
    }
    __syncthreads();

    for (int t = 0; t < TSEQ; ++t) {
        const int cur = t & 1, nxt = cur ^ 1;

        // finalize out(t-1)
        if (t > 0 && tid < 16) {
            float s = psum_s[cur][0][tid] + psum_s[cur][1][tid]
                    + psum_s[cur][2][tid] + psum_s[cur][3][tid];
            out[(size_t)(b0 + tid) * TSEQ + (t - 1)] = fast_tanh(s + bout);
        }

        // prefetch x(t+1) into regs (commit after compute)
        float4 xv;
        if (t + 1 < TSEQ)
            xv = *(const float4*)(x + (size_t)(b0 + bx) * TSEQ * FDIM
                                    + (size_t)(t + 1) * FDIM + fx);

        // init accumulators with biases
        f32x4 acc[4][2];   // 0:r 1:z 2:n-input 3:n-hidden
        #pragma unroll
        for (int j = 0; j < 2; ++j) {
            acc[0][j] = biasR[j];  acc[1][j] = biasZ[j];
            acc[2][j] = biasNI[j]; acc[3][j] = biasNH[j];
        }

        // h-part: 4 K-tiles x (r,z,nH) x 2 tiles x 3-term
        #pragma unroll
        for (int kt = 0; kt < 4; ++kt) {
            short8 bh = *(const short8*)&h_hi_s[cur][bcol][kt * 32 + g4 * 8];
            short8 bl = *(const short8*)&h_lo_s[cur][bcol][kt * 32 + g4 * 8];
            #pragma unroll
            for (int kd = 0; kd < 3; ++kd) {
                const int ai = (kd == 2) ? 3 : kd;
                #pragma unroll
                for (int j = 0; j < 2; ++j) {
                    f32x4 a = acc[ai][j];
                    a = mfma16(Whh_hi[kd][j][kt], bh, a);
                    a = mfma16(Whh_hi[kd][j][kt], bl, a);
                    a = mfma16(Whh_lo[kd][j][kt], bh, a);
                    acc[ai][j] = a;
                }
            }
        }
        // x-part: 2 K-tiles x (r,z,nI)
        #pragma unroll
        for (int kt = 0; kt < 2; ++kt) {
            short8 bh = *(const short8*)&x_hi_s[cur][bcol][kt * 32 + g4 * 8];
            short8 bl = *(const short8*)&x_lo_s[cur][bcol][kt * 32 + g4 * 8];
            #pragma unroll
            for (int kd = 0; kd < 3; ++kd) {
                const int ai = kd;   // n-gate x-part -> acc[2]
                #pragma unroll
                for (int j = 0; j < 2; ++j) {
                    f32x4 a = acc[ai][j];
                    a = mfma16(Wih_hi[kd][j][kt], bh, a);
                    a = mfma16(Wih_hi[kd][j][kt], bl, a);
                    a = mfma16(Wih_lo[kd][j][kt], bh, a);
                    acc[ai][j] = a;
                }
            }
        }

        // elementwise gates (in-register), h update, h write, out partial
        float psum = 0.0f;
        #pragma unroll
        for (int j = 0; j < 2; ++j) {
            unsigned short hh[4], hl[4];
            #pragma unroll
            for (int i = 0; i < 4; ++i) {
                float r  = fast_sig(acc[0][j][i]);
                float z  = fast_sig(acc[1][j][i]);
                float n  = fast_tanh(acc[2][j][i] + r * acc[3][j][i]);
                float hn = n + z * (h_old[j][i] - n);
                h_old[j][i] = hn;
                psum = fmaf(wout[j][i], hn, psum);
                cvt_hilo(hn, hh[i], hl[i]);
            }
            const int hoff = w * 32 + j * 16 + g4 * 4;
            uint2 ph = { (unsigned)hh[0] | ((unsigned)hh[1] << 16),
                         (unsigned)hh[2] | ((unsigned)hh[3] << 16) };
            uint2 pl = { (unsigned)hl[0] | ((unsigned)hl[1] << 16),
                         (unsigned)hl[2] | ((unsigned)hl[3] << 16) };
            *(uint2*)&h_hi_s[nxt][bcol][hoff] = ph;
            *(uint2*)&h_lo_s[nxt][bcol][hoff] = pl;
        }
        psum += __shfl_xor(psum, 16);
        psum += __shfl_xor(psum, 32);
        if (lane < 16) psum_s[nxt][w][lane] = psum;

        // commit x(t+1)
        if (t + 1 < TSEQ) {
            unsigned short h0,l0,h1,l1,h2,l2,h3,l3;
            cvt_hilo(xv.x,h0,l0); cvt_hilo(xv.y,h1,l1);
            cvt_hilo(xv.z,h2,l2); cvt_hilo(xv.w,h3,l3);
            uint2 ph = { (unsigned)h0 | ((unsigned)h1 << 16), (unsigned)h2 | ((unsigned)h3 << 16) };
            uint2 pl = { (unsigned)l0 | ((unsigned)l1 << 16), (unsigned)l2 | ((unsigned)l3 << 16) };
            *(uint2*)&x_hi_s[nxt][bx][fx] = ph;
            *(uint2*)&x_lo_s[nxt][bx][fx] = pl;
        }
        __syncthreads();
    }

    // final output (t = TSEQ-1), psum buffer = nxt(511) = 0
    if (tid < 16) {
        float s = psum_s[0][0][tid] + psum_s[0][1][tid]
                + psum_s[0][2][tid] + psum_s[0][3][tid];
        out[(size_t)(b0 + tid) * TSEQ + (TSEQ - 1)] = fast_tanh(s + bout);
    }
}

extern "C" void kernel_launch(void* const* d_in, const int* in_sizes, int n_in,
                              void* d_out, int out_size, void* d_ws, size_t ws_size,
                              hipStream_t stream) {
    const float* x     = (const float*)d_in[0];
    const float* W_ih  = (const float*)d_in[1];
    const float* W_hh  = (const float*)d_in[2];
    const float* b_ih  = (const float*)d_in[3];
    const float* b_hh  = (const float*)d_in[4];
    const float* W_out = (const float*)d_in[5];
    const float* b_out = (const float*)d_in[6];
    float* out = (float*)d_out;

    gru_mfma<<<32, 256, 0, stream>>>(x, W_ih, W_hh, b_ih, b_hh, W_out, b_out, out);
}